// Round 1
// baseline (828.686 us; speedup 1.0000x reference)
//
#include <hip/hip_runtime.h>
#include <hip/hip_bf16.h>
#include <hip/hip_fp16.h>

// MoE top-2 of 8 experts. B=4,T=2048,C=1024,FF=4096 -> N=8192 tokens.
// Plan: gate(fp32) -> route (pad segments to BM=128) -> transpose W to [n][k] f16
//       -> GEMM1 (x@W1, relu, h f16) -> GEMM2 (h@W2, weighted atomicAdd into out).

#define N_TOK 8192
#define C_DIM 1024
#define F_DIM 4096
#define BM 128
#define M_BLOCKS 136          // ceil(16384/128) + 8 experts' padding
#define A_ROWS (M_BLOCKS*BM)  // 17408

// workspace layout (bytes); total = 226,763,776 (~217 MB)
#define OFF_TOK  0u            // int[17408]
#define OFF_WGT  69632u        // float[17408]
#define OFF_MBLK 139264u       // int[136] (padded)
#define OFF_TE   140288u       // int2[8192]
#define OFF_TW   205824u       // float2[8192]
#define OFF_XB   271360u       // f16[8192*1024]
#define OFF_WT   17048576u     // f16[8*4096*1024]  (reused for W1t then W2t)
#define OFF_H    84157440u     // f16[17408*4096]

typedef __attribute__((ext_vector_type(8))) _Float16 f16x8;
typedef __attribute__((ext_vector_type(4))) float f32x4;
typedef __attribute__((ext_vector_type(8))) unsigned short u16x8;

__device__ __forceinline__ unsigned short f2h_bits(float x) {
    _Float16 h = (_Float16)x;
    return __builtin_bit_cast(unsigned short, h);
}

// async global->LDS, 16B per lane; LDS dest = wave-uniform base + lane*16
__device__ __forceinline__ void gload16(const void* g, void* l) {
    __builtin_amdgcn_global_load_lds(
        (const __attribute__((address_space(1))) unsigned int*)g,
        (__attribute__((address_space(3))) unsigned int*)l, 16, 0, 0);
}

// ---------------- gating: logits = x@Wg, softmax, top2, renormalize; also x->f16
__global__ __launch_bounds__(256) void gate_kernel(
    const float* __restrict__ x, const float* __restrict__ Wg,
    unsigned short* __restrict__ xb, int2* __restrict__ te, float2* __restrict__ tw)
{
    int w = threadIdx.x >> 6, lam = threadIdx.x & 63;
    int t = blockIdx.x * 4 + w;
    const float* xr = x + (size_t)t * C_DIM;
    unsigned short* xbr = xb + (size_t)t * C_DIM;
    float acc[8] = {0,0,0,0,0,0,0,0};
    for (int it = 0; it < C_DIM/64; ++it) {
        int c = it*64 + lam;
        float v = xr[c];
        xbr[c] = f2h_bits(v);
        const float4* wg = (const float4*)(Wg + c*8);
        float4 a = wg[0], b = wg[1];
        acc[0] += v*a.x; acc[1] += v*a.y; acc[2] += v*a.z; acc[3] += v*a.w;
        acc[4] += v*b.x; acc[5] += v*b.y; acc[6] += v*b.z; acc[7] += v*b.w;
    }
    #pragma unroll
    for (int off = 32; off > 0; off >>= 1)
        #pragma unroll
        for (int e = 0; e < 8; ++e)
            acc[e] += __shfl_xor(acc[e], off);
    if (lam == 0) {
        float m = acc[0];
        #pragma unroll
        for (int e = 1; e < 8; ++e) m = fmaxf(m, acc[e]);
        float ex[8], d = 0.f;
        #pragma unroll
        for (int e = 0; e < 8; ++e) { ex[e] = expf(acc[e] - m); d += ex[e]; }
        int e0 = 0;
        #pragma unroll
        for (int e = 1; e < 8; ++e) if (acc[e] > acc[e0]) e0 = e;
        int e1 = (e0 == 0) ? 1 : 0;
        #pragma unroll
        for (int e = 0; e < 8; ++e) if (e != e0 && acc[e] > acc[e1]) e1 = e;
        float g0 = ex[e0]/d, g1 = ex[e1]/d;
        float s = g0 + g1 + 1e-9f;
        te[t] = make_int2(e0, e1);
        tw[t] = make_float2(g0/s, g1/s);
    }
}

// ---------------- routing: counts -> 128-aligned segments -> scatter token lists
__global__ __launch_bounds__(1024) void route_kernel(
    const int2* __restrict__ te, const float2* __restrict__ tw,
    int* __restrict__ tok, float* __restrict__ wgt, int* __restrict__ mblk)
{
    __shared__ int cnt[8], curs[8], base[8], alen[8];
    int tid = threadIdx.x;
    if (tid < 8) { cnt[tid] = 0; curs[tid] = 0; }
    __syncthreads();
    for (int t = tid; t < N_TOK; t += 1024) {
        int2 ee = te[t];
        atomicAdd(&cnt[ee.x], 1); atomicAdd(&cnt[ee.y], 1);
    }
    __syncthreads();
    if (tid == 0) {
        int b = 0;
        for (int e = 0; e < 8; ++e) {
            base[e] = b;
            int a = ((cnt[e] + BM - 1) / BM) * BM;
            alen[e] = a;
            b += a;
        }
    }
    __syncthreads();
    for (int i = tid; i < A_ROWS; i += 1024) tok[i] = -1;
    for (int mb = tid; mb < M_BLOCKS; mb += 1024) {
        int r = mb * BM, ef = 0;
        for (int e = 0; e < 8; ++e)
            if (r >= base[e] && r < base[e] + alen[e]) ef = e;
        mblk[mb] = ef;
    }
    __syncthreads();
    for (int t = tid; t < N_TOK; t += 1024) {
        int2 ee = te[t]; float2 ww = tw[t];
        int p = atomicAdd(&curs[ee.x], 1);
        tok[base[ee.x] + p] = t; wgt[base[ee.x] + p] = ww.x;
        p = atomicAdd(&curs[ee.y], 1);
        tok[base[ee.y] + p] = t; wgt[base[ee.y] + p] = ww.y;
    }
}

// ---------------- transpose+cvt: [E][R][Cd] fp32 -> [E][Cd][R] f16
__global__ __launch_bounds__(256) void transpose_kernel(
    const float* __restrict__ src, unsigned short* __restrict__ dst, int R, int Cd)
{
    __shared__ float tile[64][65];
    int tcN = Cd >> 6;
    int tilesPerE = (R >> 6) * tcN;
    int bid = blockIdx.x;
    int e = bid / tilesPerE;
    int tt = bid - e * tilesPerE;
    int tr = tt / tcN, tc = tt - tr * tcN;
    int R0 = tr << 6, C0 = tc << 6;
    const float* se = src + (size_t)e * R * Cd;
    unsigned short* de = dst + (size_t)e * R * Cd;
    int tid = threadIdx.x;
    int col4 = (tid & 15) << 2;
    int row0 = tid >> 4;
    #pragma unroll
    for (int j = 0; j < 4; ++j) {
        int row = row0 + j*16;
        float4 v = *(const float4*)(se + (size_t)(R0+row)*Cd + C0 + col4);
        tile[row][col4+0] = v.x; tile[row][col4+1] = v.y;
        tile[row][col4+2] = v.z; tile[row][col4+3] = v.w;
    }
    __syncthreads();
    int oc = tid >> 2;   // 0..63 output row (original col)
    int og = tid & 3;    // quarter of the 64 output cols
    u16x8 o0, o1;
    #pragma unroll
    for (int i = 0; i < 8; ++i) o0[i] = f2h_bits(tile[og*16 + i][oc]);
    #pragma unroll
    for (int i = 0; i < 8; ++i) o1[i] = f2h_bits(tile[og*16 + 8 + i][oc]);
    unsigned short* dp = de + (size_t)(C0+oc)*R + R0 + og*16;
    *(u16x8*)dp = o0;
    *(u16x8*)(dp + 8) = o1;
}

// ---------------- 128x128x32 f16 MFMA GEMM, global_load_lds staging, chunk-swizzled LDS
// A[m][k] (gathered x rows or h rows), B = Wt[e][n][k]; D = A*B.
// LDS tile [128 rows][32 k] f16 = 64B rows; chunk (16B = 8 f16) swizzle: c' = (c + (row>>1)) & 3.
template<int K_DIM, int N_COLS, bool GATHER_A, bool RELU_H>
__global__ __launch_bounds__(256) void gemm_kernel(
    const unsigned short* __restrict__ Asrc, const unsigned short* __restrict__ Wt,
    const int* __restrict__ tok, const float* __restrict__ wgt,
    const int* __restrict__ mblk,
    unsigned short* __restrict__ hout, float* __restrict__ out)
{
    constexpr int KT = K_DIM / 32;
    __shared__ unsigned short As[BM*32];
    __shared__ unsigned short Bs[BM*32];
    int nb = blockIdx.x, mb = blockIdx.y;
    int e = mblk[mb];
    int aBase = mb*BM, nBase = nb*128;
    int tid = threadIdx.x, w = tid >> 6, lam = tid & 63;
    int wm = w >> 1, wn = w & 1;
    int rowInG = lam >> 2, cpr = lam & 3;

    const char* srcA[2]; const char* srcB[2];
    char* ldsA[2]; char* ldsB[2];
    #pragma unroll
    for (int i = 0; i < 2; ++i) {
        int g = w*2 + i;
        int ra = g*16 + rowInG;                 // tile-local row this lane stages
        int cg = (cpr - (ra >> 1)) & 3;         // inverse swizzle: global chunk for LDS slot cpr
        long arow;
        if (GATHER_A) { int tkn = tok[aBase + ra]; if (tkn < 0) tkn = 0; arow = tkn; }
        else          { arow = aBase + ra; }
        srcA[i] = (const char*)(Asrc + arow*(long)K_DIM) + cg*16;
        srcB[i] = (const char*)(Wt + ((long)e*N_COLS + nBase + ra)*(long)K_DIM) + cg*16;
        ldsA[i] = (char*)As + g*1024;
        ldsB[i] = (char*)Bs + g*1024;
    }

    const f32x4 z = {0.f, 0.f, 0.f, 0.f};
    f32x4 acc[4][4];
    #pragma unroll
    for (int mi = 0; mi < 4; ++mi)
        #pragma unroll
        for (int ni = 0; ni < 4; ++ni) acc[mi][ni] = z;

    for (int kt = 0; kt < KT; ++kt) {
        __syncthreads();                         // prior frag reads done before overwrite
        long ko = (long)kt * 64;                 // 32 f16 per K step
        gload16(srcA[0] + ko, ldsA[0]);
        gload16(srcA[1] + ko, ldsA[1]);
        gload16(srcB[0] + ko, ldsB[0]);
        gload16(srcB[1] + ko, ldsB[1]);
        __syncthreads();                         // drains vmcnt, data visible

        f16x8 af[4], bf[4];
        #pragma unroll
        for (int mi = 0; mi < 4; ++mi) {
            int r = wm*64 + mi*16 + (lam & 15);
            int cs = ((lam >> 4) + (r >> 1)) & 3;
            af[mi] = *(const f16x8*)((const char*)As + r*64 + cs*16);
        }
        #pragma unroll
        for (int ni = 0; ni < 4; ++ni) {
            int r = wn*64 + ni*16 + (lam & 15);
            int cs = ((lam >> 4) + (r >> 1)) & 3;
            bf[ni] = *(const f16x8*)((const char*)Bs + r*64 + cs*16);
        }
        #pragma unroll
        for (int mi = 0; mi < 4; ++mi)
            #pragma unroll
            for (int ni = 0; ni < 4; ++ni)
                acc[mi][ni] = __builtin_amdgcn_mfma_f32_16x16x32_f16(af[mi], bf[ni], acc[mi][ni], 0, 0, 0);
    }

    // epilogue: C/D layout col=lane&15, row=(lane>>4)*4+j (guide m89)
    #pragma unroll
    for (int mi = 0; mi < 4; ++mi) {
        int r0 = aBase + wm*64 + mi*16 + (lam >> 4)*4;
        #pragma unroll
        for (int ni = 0; ni < 4; ++ni) {
            int col = nBase + wn*64 + ni*16 + (lam & 15);
            f32x4 v = acc[mi][ni];
            if (RELU_H) {
                #pragma unroll
                for (int j = 0; j < 4; ++j)
                    hout[(size_t)(r0+j)*N_COLS + col] = f2h_bits(fmaxf(v[j], 0.f));
            } else {
                #pragma unroll
                for (int j = 0; j < 4; ++j) {
                    int ar = r0 + j;
                    int tkn = tok[ar];
                    if (tkn >= 0) atomicAdd(out + (size_t)tkn*C_DIM + col, wgt[ar]*v[j]);
                }
            }
        }
    }
}

extern "C" void kernel_launch(void* const* d_in, const int* in_sizes, int n_in,
                              void* d_out, int out_size, void* d_ws, size_t ws_size,
                              hipStream_t stream)
{
    const float* x  = (const float*)d_in[0];
    const float* Wg = (const float*)d_in[1];
    const float* W1 = (const float*)d_in[2];
    const float* W2 = (const float*)d_in[3];
    float* out = (float*)d_out;
    char* ws = (char*)d_ws;

    int*    tok  = (int*)(ws + OFF_TOK);
    float*  wgt  = (float*)(ws + OFF_WGT);
    int*    mblk = (int*)(ws + OFF_MBLK);
    int2*   te   = (int2*)(ws + OFF_TE);
    float2* tw   = (float2*)(ws + OFF_TW);
    unsigned short* xb = (unsigned short*)(ws + OFF_XB);
    unsigned short* wt = (unsigned short*)(ws + OFF_WT);
    unsigned short* h  = (unsigned short*)(ws + OFF_H);

    hipMemsetAsync(d_out, 0, (size_t)out_size * sizeof(float), stream);
    gate_kernel<<<N_TOK/4, 256, 0, stream>>>(x, Wg, xb, te, tw);
    route_kernel<<<1, 1024, 0, stream>>>(te, tw, tok, wgt, mblk);
    transpose_kernel<<<8192, 256, 0, stream>>>(W1, wt, 1024, 4096);
    gemm_kernel<1024, 4096, true,  true ><<<dim3(32, M_BLOCKS), 256, 0, stream>>>(xb, wt, tok, wgt, mblk, h, nullptr);
    transpose_kernel<<<8192, 256, 0, stream>>>(W2, wt, 4096, 1024);
    gemm_kernel<4096, 1024, false, false><<<dim3(8, M_BLOCKS), 256, 0, stream>>>(h, wt, tok, wgt, mblk, nullptr, out);
}